// Round 8
// baseline (830.106 us; speedup 1.0000x reference)
//
#include <hip/hip_runtime.h>
#include <hip/hip_bf16.h>
#include <stdint.h>

#define S_LEN 2048
#define NROW  4096            // B*S
#define DQKV  3072            // 2048 Q + 512 K + 512 V

typedef unsigned short u16;
typedef __attribute__((ext_vector_type(8))) short bf16x8;
typedef __attribute__((ext_vector_type(4))) float f32x4;

__device__ __forceinline__ float bf2f(u16 v) {
  unsigned int u = ((unsigned int)v) << 16;
  return __builtin_bit_cast(float, u);
}
__device__ __forceinline__ u16 f2bf(float f) {
  unsigned int u = __builtin_bit_cast(unsigned int, f);
  u += 0x7FFFu + ((u >> 16) & 1u);
  return (u16)(u >> 16);
}
__device__ __forceinline__ void async16(const void* g, void* l) {
  __builtin_amdgcn_global_load_lds(
      (const __attribute__((address_space(1))) unsigned int*)(uintptr_t)g,
      (__attribute__((address_space(3))) unsigned int*)(uintptr_t)l, 16, 0, 0);
}
#define SB()   __builtin_amdgcn_sched_barrier(0)
#define WLG0   do { asm volatile("s_waitcnt lgkmcnt(0)" ::: "memory"); SB(); } while (0)
#define WLG8   do { asm volatile("s_waitcnt lgkmcnt(8)" ::: "memory"); } while (0)
#define WVM4   do { asm volatile("s_waitcnt vmcnt(4)" ::: "memory"); SB(); } while (0)
#define WVM0   do { asm volatile("s_waitcnt vmcnt(0)" ::: "memory"); SB(); } while (0)
#define BAR()  __builtin_amdgcn_s_barrier()

// ---------------- transpose f32 [R][C] -> bf16 [C][R] ----------------
__global__ __launch_bounds__(256) void transpose_f32_bf16(
    const float* __restrict__ in, u16* __restrict__ out, int R, int C) {
  __shared__ float t[32][33];
  const int bx = blockIdx.x * 32;
  const int by = blockIdx.y * 32;
  const int tx = threadIdx.x, ty = threadIdx.y;   // 32 x 8
#pragma unroll
  for (int i = 0; i < 32; i += 8)
    t[ty + i][tx] = in[(size_t)(by + ty + i) * C + bx + tx];
  __syncthreads();
#pragma unroll
  for (int i = 0; i < 32; i += 8)
    out[(size_t)(bx + ty + i) * R + by + tx] = f2bf(t[tx][ty + i]);
}

// ---------------- RoPE tables ----------------
__global__ __launch_bounds__(256) void rope_tables(float* __restrict__ cosT,
                                                   float* __restrict__ sinT) {
  int idx = blockIdx.x * 256 + threadIdx.x;   // 2048*64
  int i = idx & 63, s = idx >> 6;
  float inv = powf(10000.0f, -2.0f * (float)i / 128.0f);
  float ang = (float)s * inv;
  cosT[idx] = cosf(ang);
  sinT[idx] = sinf(ang);
}

// ---------------- RoPE in-place on QKV ----------------
__global__ __launch_bounds__(256) void rope_apply(u16* __restrict__ QKV,
                                                  const float* __restrict__ cosT,
                                                  const float* __restrict__ sinT) {
  int idx = blockIdx.x * 256 + threadIdx.x;        // NROW*20*64
  int i = idx & 63;
  int h20 = (idx >> 6) % 20;
  int row = idx / (64 * 20);
  int s = row & (S_LEN - 1);
  int col = (h20 < 16) ? (h20 * 128) : (2048 + (h20 - 16) * 128);
  size_t base = (size_t)row * DQKV + col;
  float v1 = bf2f(QKV[base + i]);
  float v2 = bf2f(QKV[base + 64 + i]);
  float c = cosT[s * 64 + i], sn = sinT[s * 64 + i];
  QKV[base + i]      = f2bf(v1 * c - v2 * sn);
  QKV[base + 64 + i] = f2bf(v1 * sn + v2 * c);
}

// ---------------- RMSNorm: f32 [rows][2048] -> bf16 ----------------
__global__ __launch_bounds__(256) void rmsnorm_kernel(const float* __restrict__ x,
                                                      const float* __restrict__ g,
                                                      u16* __restrict__ out) {
  const int row = blockIdx.x, tid = threadIdx.x;
  const float* xr = x + (size_t)row * 2048;
  float4 a = ((const float4*)xr)[tid * 2];
  float4 b = ((const float4*)xr)[tid * 2 + 1];
  float ss = a.x*a.x + a.y*a.y + a.z*a.z + a.w*a.w
           + b.x*b.x + b.y*b.y + b.z*b.z + b.w*b.w;
#pragma unroll
  for (int m = 1; m < 64; m <<= 1) ss += __shfl_xor(ss, m, 64);
  __shared__ float red[4];
  if ((tid & 63) == 0) red[tid >> 6] = ss;
  __syncthreads();
  float tot = red[0] + red[1] + red[2] + red[3];
  float rms = rsqrtf(tot * (1.0f / 2048.0f) + 1e-5f);
  const int c = tid * 8;
  float v[8] = {a.x,a.y,a.z,a.w,b.x,b.y,b.z,b.w};
  u16 o[8];
#pragma unroll
  for (int j = 0; j < 8; j++) o[j] = f2bf(v[j] * rms * g[c + j]);
  *(uint4*)(out + (size_t)row * 2048 + c) = *(uint4*)o;
}

// ================= uniform m201-style 256x256 GEMM =================
// BM=BN=256, BK=64, 512 thr, 8 waves (2m x 4n), wave tile 128x64 (8m x 4n frags).
// 4 uniform phases/K-tile, quadrants (m0,n0)(m1,n0)(m1,n1)(m0,n1), 16 MFMA each.
// Reads/phase: 12 / 8 / 4 / 8 (A re-read at p3, B/A carried exactly 1 phase).
// Stages: p0: A-h0(t+1), p1: A-h1(t+1) [dead buffer], p3: B-h0+h1(t+2) [current
// buffer, after its last read at p2]. vmcnt(4) once per tile at p3.
// MODE 0: bf16 out. MODE 1: f32 out = acc + res. MODE 2: f32 out = acc (split-K
// slice, kslice = wg>>7). MODE 3: swiglu — B = Bt0(g-panel)||Bt1(u-panel),
// epilogue combines silu(g+bias)*(u+bias2) across waves via LDS.
template <int MODE>
__global__ __launch_bounds__(512, 2) void gemmU(
    const u16* __restrict__ A, const u16* __restrict__ Bt0, const u16* __restrict__ Bt1,
    int Klen, int Kstride, int Nout,
    const float* __restrict__ bias, const float* __restrict__ bias2,
    const float* __restrict__ res, u16* __restrict__ outb, float* __restrict__ outf) {
  __shared__ char ldsA[2 * 32768] __attribute__((aligned(16)));
  __shared__ char ldsB[2 * 32768] __attribute__((aligned(16)));
  const int t = threadIdx.x;
  const int nwg = gridDim.x;
  int wg = ((int)blockIdx.x & 7) * (nwg >> 3) + ((int)blockIdx.x >> 3);
  int kslice = 0;
  if (MODE == 2) { kslice = wg >> 7; wg &= 127; }
  const int m0 = (wg & 15) * 256;          // m-fast for XCD B-panel locality
  const int nIdx = wg >> 4;
  const int l = t & 63, w = t >> 6;
  const int wm = w >> 2, wn = w & 3;
  const int lr = l & 15, lg = l >> 4;

  const size_t Ks2 = (size_t)Kstride * 2;
  const int pr = t >> 3;                        // 0..63
  const int ckb = ((t & 7) ^ (pr & 7)) * 16;    // inverse-swizzled source chunk
  const int t16 = t * 16;
  const size_t koff = (size_t)kslice * 8192;    // bytes (4096 cols * 2B)
  const char* aSrc = (const char*)A + (size_t)(m0 + pr) * Ks2 + koff + ckb;
  const char* b0Src;
  const char* b1Src;
  if constexpr (MODE == 3) {
    b0Src = (const char*)Bt0 + (size_t)(nIdx * 128 + pr) * Ks2 + ckb;
    b1Src = (const char*)Bt1 + (size_t)(nIdx * 128 + pr) * Ks2 + ckb;
  } else {
    b0Src = (const char*)Bt0 + (size_t)(nIdx * 256 + pr) * Ks2 + koff + ckb;
    b1Src = b0Src + (size_t)128 * Ks2;
  }

  auto ST_A = [&](int h, int kt, int buf) {
    char* d = ldsA + buf * 32768 + h * 16384 + t16;
    const char* s = aSrc + (size_t)(h * 128) * Ks2 + (size_t)kt * 128;
    async16(s, d);
    async16(s + (size_t)64 * Ks2, d + 8192);
  };
  auto ST_B = [&](int h, int kt, int buf) {
    char* d = ldsB + buf * 32768 + h * 16384 + t16;
    const char* s = (h ? b1Src : b0Src) + (size_t)kt * 128;
    async16(s, d);
    async16(s + (size_t)64 * Ks2, d + 8192);
  };

  const int NT = Klen >> 6;
  // prologue: A(0), B(0) fully; B(1) both halves. A(1) staged at tile0 p0/p1.
  ST_A(0, 0, 0); ST_A(1, 0, 0); ST_B(0, 0, 0); ST_B(1, 0, 0);
  ST_B(0, 1, 1); ST_B(1, 1, 1);
  WVM4;            // A(0)+B(0) landed; B(1) in flight
  BAR();

  const int key = lr & 7;
  const int c0 = (lg ^ key) * 16;
  const int c1 = ((4 + lg) ^ key) * 16;
  const int aBase = wm * 16384 + lr * 128;
  const int bBase = (wn >> 1) * 16384 + ((wn & 1) * 64 + lr) * 128;

  f32x4 acc[8][4] = {};

  for (int kt = 0; kt < NT; ++kt) {
    const int bufc = kt & 1, bufn = bufc ^ 1;
    const int t1 = (kt + 1 < NT) ? kt + 1 : 0;
    const int t2 = (kt + 2 < NT) ? kt + 2 : kt + 2 - NT;
    const char* sA = ldsA + bufc * 32768;
    const char* sB = ldsB + bufc * 32768;
    bf16x8 a0[4][2], a1[4][2], b0[2][2], b1[2][2];
    // ---- p0: quadrant (m0-3, n0-1). reads 12; stage A-h0(t+1)
#pragma unroll
    for (int m = 0; m < 4; m++) {
      a0[m][0] = *(const bf16x8*)(sA + aBase + m * 2048 + c0);
      a0[m][1] = *(const bf16x8*)(sA + aBase + m * 2048 + c1);
    }
#pragma unroll
    for (int n = 0; n < 2; n++) {
      b0[n][0] = *(const bf16x8*)(sB + bBase + n * 2048 + c0);
      b0[n][1] = *(const bf16x8*)(sB + bBase + n * 2048 + c1);
    }
    ST_A(0, t1, bufn);
    WLG8;
    SB(); BAR();
    WLG0;
    __builtin_amdgcn_s_setprio(1);
#pragma unroll
    for (int m = 0; m < 4; m++)
#pragma unroll
      for (int n = 0; n < 2; n++) {
        acc[m][n] = __builtin_amdgcn_mfma_f32_16x16x32_bf16(a0[m][0], b0[n][0], acc[m][n], 0, 0, 0);
        acc[m][n] = __builtin_amdgcn_mfma_f32_16x16x32_bf16(a0[m][1], b0[n][1], acc[m][n], 0, 0, 0);
      }
    __builtin_amdgcn_s_setprio(0);
    SB(); BAR();
    // ---- p1: quadrant (m4-7, n0-1). reads 8 (carry b0); stage A-h1(t+1)
#pragma unroll
    for (int m = 0; m < 4; m++) {
      a1[m][0] = *(const bf16x8*)(sA + aBase + (4 + m) * 2048 + c0);
      a1[m][1] = *(const bf16x8*)(sA + aBase + (4 + m) * 2048 + c1);
    }
    ST_A(1, t1, bufn);
    SB(); BAR();
    WLG0;
    __builtin_amdgcn_s_setprio(1);
#pragma unroll
    for (int m = 0; m < 4; m++)
#pragma unroll
      for (int n = 0; n < 2; n++) {
        acc[4 + m][n] = __builtin_amdgcn_mfma_f32_16x16x32_bf16(a1[m][0], b0[n][0], acc[4 + m][n], 0, 0, 0);
        acc[4 + m][n] = __builtin_amdgcn_mfma_f32_16x16x32_bf16(a1[m][1], b0[n][1], acc[4 + m][n], 0, 0, 0);
      }
    __builtin_amdgcn_s_setprio(0);
    SB(); BAR();
    // ---- p2: quadrant (m4-7, n2-3). reads 4 (carry a1)
#pragma unroll
    for (int n = 0; n < 2; n++) {
      b1[n][0] = *(const bf16x8*)(sB + bBase + (2 + n) * 2048 + c0);
      b1[n][1] = *(const bf16x8*)(sB + bBase + (2 + n) * 2048 + c1);
    }
    SB(); BAR();
    WLG0;
    __builtin_amdgcn_s_setprio(1);
#pragma unroll
    for (int m = 0; m < 4; m++)
#pragma unroll
      for (int n = 0; n < 2; n++) {
        acc[4 + m][2 + n] = __builtin_amdgcn_mfma_f32_16x16x32_bf16(a1[m][0], b1[n][0], acc[4 + m][2 + n], 0, 0, 0);
        acc[4 + m][2 + n] = __builtin_amdgcn_mfma_f32_16x16x32_bf16(a1[m][1], b1[n][1], acc[4 + m][2 + n], 0, 0, 0);
      }
    __builtin_amdgcn_s_setprio(0);
    SB(); BAR();
    // ---- p3: quadrant (m0-3, n2-3). re-read a (8, carry b1);
    //          stage B-h0+h1(t+2) into current buf (B dead after p2); vmcnt(4)
#pragma unroll
    for (int m = 0; m < 4; m++) {
      a0[m][0] = *(const bf16x8*)(sA + aBase + m * 2048 + c0);
      a0[m][1] = *(const bf16x8*)(sA + aBase + m * 2048 + c1);
    }
    ST_B(0, t2, bufc);
    ST_B(1, t2, bufc);
    WVM4;       // certifies A(t+1) [p0/p1] and B(t+1) [last tile p3]
    SB(); BAR();
    WLG0;
    __builtin_amdgcn_s_setprio(1);
#pragma unroll
    for (int m = 0; m < 4; m++)
#pragma unroll
      for (int n = 0; n < 2; n++) {
        acc[m][2 + n] = __builtin_amdgcn_mfma_f32_16x16x32_bf16(a0[m][0], b1[n][0], acc[m][2 + n], 0, 0, 0);
        acc[m][2 + n] = __builtin_amdgcn_mfma_f32_16x16x32_bf16(a0[m][1], b1[n][1], acc[m][2 + n], 0, 0, 0);
      }
    __builtin_amdgcn_s_setprio(0);
    SB(); BAR();
  }

  if constexpr (MODE == 3) {
    // drain wrapped stages before LDS reuse, then cross-wave silu combine
    WVM0;
    BAR();
    auto epPtr = [&](int row, int cc8) -> u16* {
      char* base = (row < 128) ? ldsA : ldsB;
      int sc8 = cc8 ^ ((row ^ (row >> 3)) & 7);
      return (u16*)(base + (row & 127) * 512 + sc8 * 16);
    };
#pragma unroll
    for (int m = 0; m < 8; m++)
#pragma unroll
      for (int n = 0; n < 4; n++)
#pragma unroll
        for (int r = 0; r < 4; r++) {
          int row = wm * 128 + m * 16 + lg * 4 + r;
          int cc = wn * 64 + n * 16 + lr;
          epPtr(row, cc >> 3)[cc & 7] = f2bf(acc[m][n][r]);
        }
    BAR();
    const int cg = (t & 15) * 8;
    const int rb = (t >> 4) * 8;
    const int gcolb = nIdx * 128 + cg;
    float bgv[8], buv[8];
#pragma unroll
    for (int j = 0; j < 8; j++) { bgv[j] = bias[gcolb + j]; buv[j] = bias2[gcolb + j]; }
#pragma unroll
    for (int i = 0; i < 8; i++) {
      int row = rb + i;
      bf16x8 g8 = *(const bf16x8*)epPtr(row, cg >> 3);
      bf16x8 u8 = *(const bf16x8*)epPtr(row, (128 + cg) >> 3);
      u16 o[8];
#pragma unroll
      for (int j = 0; j < 8; j++) {
        float gv = bf2f((u16)g8[j]) + bgv[j];
        float uv = bf2f((u16)u8[j]) + buv[j];
        o[j] = f2bf(gv / (1.0f + __expf(-gv)) * uv);
      }
      *(uint4*)(outb + (size_t)(m0 + row) * Nout + gcolb) = *(uint4*)o;
    }
  } else {
    float* outfe = outf;
    if constexpr (MODE == 2) outfe = outf + (size_t)kslice * NROW * 2048;
    const int n0 = nIdx * 256;
#pragma unroll
    for (int m = 0; m < 8; m++) {
      const int row = m0 + wm * 128 + m * 16 + lg * 4;
#pragma unroll
      for (int n = 0; n < 4; n++) {
        const int col = n0 + wn * 64 + n * 16 + lr;
#pragma unroll
        for (int r = 0; r < 4; r++) {
          const size_t idx = (size_t)(row + r) * Nout + col;
          if (MODE == 0)      outb[idx] = f2bf(acc[m][n][r]);
          else if (MODE == 1) outfe[idx] = acc[m][n][r] + res[idx];
          else                outfe[idx] = acc[m][n][r];
        }
      }
    }
  }
}

// ---------------- Wd split-K combine: out = t0 + t1 + h + bd ----------------
__global__ __launch_bounds__(256) void combine_wd(
    const float* __restrict__ t0, const float* __restrict__ t1,
    const float* __restrict__ h, const float* __restrict__ bd,
    float* __restrict__ out) {
  const int stride = gridDim.x * 256;
  for (int i = blockIdx.x * 256 + threadIdx.x; i < NROW * 512; i += stride) {
    float4 a = ((const float4*)t0)[i];
    float4 b = ((const float4*)t1)[i];
    float4 c = ((const float4*)h)[i];
    float4 d = ((const float4*)bd)[i & 511];
    float4 o;
    o.x = a.x + b.x + c.x + d.x;
    o.y = a.y + b.y + c.y + d.y;
    o.z = a.z + b.z + c.z + d.z;
    o.w = a.w + b.w + c.w + d.w;
    ((float4*)out)[i] = o;
  }
}

// ---------------- Flash attention (causal, GQA kv = hq%4) ----------------
__global__ __launch_bounds__(256) void attn_kernel(const u16* __restrict__ QKV,
                                                   u16* __restrict__ O) {
  const int bid = blockIdx.x;
  const int half = bid >> 8, rr = bid & 255;
  const int bh = rr >> 3, tt = rr & 7;
  const int qtile = half ? (15 - tt) : tt;
  const int b = bh >> 4, hq = bh & 15, g = hq & 3;
  const int q0 = qtile * 128;
  const int tid = threadIdx.x, l = tid & 63, w = tid >> 6;
  const int lr = l & 15, lg = l >> 4;

  __shared__ u16 kT[64 * 128] __attribute__((aligned(16)));
  __shared__ u16 vT[128 * 64] __attribute__((aligned(16)));
  __shared__ u16 pT[4][32 * 72] __attribute__((aligned(16)));

  const float scale = 0.08838834764831845f;   // 1/sqrt(128)

  bf16x8 qF[2][4];
  const int qrow_base = b * S_LEN + q0 + w * 32;
#pragma unroll
  for (int mq = 0; mq < 2; mq++)
#pragma unroll
    for (int kk = 0; kk < 4; kk++)
      qF[mq][kk] = *(const bf16x8*)(QKV + (size_t)(qrow_base + mq * 16 + lr) * DQKV
                                    + hq * 128 + kk * 32 + lg * 8);

  f32x4 o_acc[2][8] = {};
  float m_run[2][4], l_run[2][4];
#pragma unroll
  for (int mq = 0; mq < 2; mq++)
#pragma unroll
    for (int r = 0; r < 4; r++) { m_run[mq][r] = -1e30f; l_run[mq][r] = 0.0f; }

  const int qmin_w = q0 + w * 32;
  const int nt = (q0 + 128) >> 6;

  for (int it = 0; it < nt; ++it) {
    const int t0 = it * 64;
    __syncthreads();
    {
      const int rbase = tid >> 3;
      const int c16 = (tid & 7) * 16;
#pragma unroll
      for (int pass = 0; pass < 2; ++pass) {
        const int r = rbase + pass * 32;
        const u16* src = QKV + (size_t)(b * S_LEN + t0 + r) * DQKV + 2048 + g * 128 + c16;
        const int rk = r & 7;
#pragma unroll
        for (int jj = 0; jj < 2; ++jj) {
          bf16x8 kv = *(const bf16x8*)(src + jj * 8);
          const int chunk = (c16 >> 3) + jj;
          *(bf16x8*)&kT[r * 128 + ((chunk ^ rk) << 3)] = kv;
        }
#pragma unroll
        for (int jj = 0; jj < 2; ++jj) {
          bf16x8 vv = *(const bf16x8*)(src + 512 + jj * 8);
#pragma unroll
          for (int j = 0; j < 8; ++j) {
            const int d = c16 + jj * 8 + j;
            const int keyv = (d ^ (d >> 4)) & 7;
            vT[d * 64 + (r & 7) + (((r >> 3) ^ keyv) << 3)] = (u16)vv[j];
          }
        }
      }
    }
    __syncthreads();

    if (t0 <= qmin_w + 31) {
      f32x4 sc[2][4] = {};
#pragma unroll
      for (int mt = 0; mt < 4; mt++) {
        const int tq = mt * 16 + lr;
        const int tk = tq & 7;
#pragma unroll
        for (int kk = 0; kk < 4; kk++) {
          bf16x8 kF = *(const bf16x8*)&kT[tq * 128 + (((kk * 4 + lg) ^ tk) << 3)];
          sc[0][mt] = __builtin_amdgcn_mfma_f32_16x16x32_bf16(qF[0][kk], kF, sc[0][mt], 0, 0, 0);
          sc[1][mt] = __builtin_amdgcn_mfma_f32_16x16x32_bf16(qF[1][kk], kF, sc[1][mt], 0, 0, 0);
        }
      }
      const bool needMask = (t0 + 63 > qmin_w);
#pragma unroll
      for (int mq = 0; mq < 2; mq++)
#pragma unroll
        for (int mt = 0; mt < 4; mt++)
#pragma unroll
          for (int r = 0; r < 4; r++) {
            float v = sc[mq][mt][r] * scale;
            if (needMask) {
              int qg = qmin_w + mq * 16 + lg * 4 + r;
              int tg = t0 + mt * 16 + lr;
              if (tg > qg) v = -1e30f;
            }
            sc[mq][mt][r] = v;
          }
#pragma unroll
      for (int mq = 0; mq < 2; mq++) {
        float al[4];
#pragma unroll
        for (int r = 0; r < 4; r++) {
          float tmax = fmaxf(fmaxf(sc[mq][0][r], sc[mq][1][r]),
                             fmaxf(sc[mq][2][r], sc[mq][3][r]));
#pragma unroll
          for (int m = 1; m < 16; m <<= 1) tmax = fmaxf(tmax, __shfl_xor(tmax, m, 64));
          float mn = fmaxf(m_run[mq][r], tmax);
          float a = __expf(m_run[mq][r] - mn);
          m_run[mq][r] = mn;
          float rs = 0.0f;
#pragma unroll
          for (int mt = 0; mt < 4; mt++) {
            float pv = __expf(sc[mq][mt][r] - mn);
            sc[mq][mt][r] = pv;
            rs += pv;
          }
#pragma unroll
          for (int m = 1; m < 16; m <<= 1) rs += __shfl_xor(rs, m, 64);
          l_run[mq][r] = l_run[mq][r] * a + rs;
          al[r] = a;
        }
#pragma unroll
        for (int n = 0; n < 8; n++)
#pragma unroll
          for (int r = 0; r < 4; r++) o_acc[mq][n][r] *= al[r];
#pragma unroll
        for (int mt = 0; mt < 4; mt++)
#pragma unroll
          for (int r = 0; r < 4; r++)
            pT[w][(mq * 16 + lg * 4 + r) * 72 + mt * 16 + lr] = f2bf(sc[mq][mt][r]);
      }
      bf16x8 pF[2][2];
#pragma unroll
      for (int mq = 0; mq < 2; mq++)
#pragma unroll
        for (int ktp = 0; ktp < 2; ktp++)
          pF[mq][ktp] = *(const bf16x8*)&pT[w][(mq * 16 + lr) * 72 + ktp * 32 + lg * 8];
#pragma unroll
      for (int ktp = 0; ktp < 2; ktp++)
#pragma unroll
        for (int n = 0; n < 8; n++) {
          const int d = n * 16 + lr;
          const int keyv = (d ^ (d >> 4)) & 7;
          bf16x8 vF = *(const bf16x8*)&vT[d * 64 + (((ktp * 4 + lg) ^ keyv) << 3)];
          o_acc[0][n] = __builtin_amdgcn_mfma_f32_16x16x32_bf16(pF[0][ktp], vF, o_acc[0][n], 0, 0, 0);
          o_acc[1][n] = __builtin_amdgcn_mfma_f32_16x16x32_bf16(pF[1][ktp], vF, o_acc[1][n], 0, 0, 0);
        }
    }
  }
#pragma unroll
  for (int mq = 0; mq < 2; mq++)
#pragma unroll
    for (int n = 0; n < 8; n++)
#pragma unroll
      for (int r = 0; r < 4; r++) {
        float v = o_acc[mq][n][r] / l_run[mq][r];
        int row = b * S_LEN + q0 + w * 32 + mq * 16 + lg * 4 + r;
        int col = hq * 128 + n * 16 + lr;
        O[(size_t)row * 2048 + col] = f2bf(v);
      }
}

// ---------------- launch ----------------
extern "C" void kernel_launch(void* const* d_in, const int* in_sizes, int n_in,
                              void* d_out, int out_size, void* d_ws, size_t ws_size,
                              hipStream_t stream) {
  const float* x  = (const float*)d_in[0];
  const float* Wq = (const float*)d_in[2];
  const float* Wk = (const float*)d_in[3];
  const float* Wv = (const float*)d_in[4];
  const float* Wo = (const float*)d_in[5];
  const float* Wg = (const float*)d_in[6];
  const float* bg = (const float*)d_in[7];
  const float* Wu = (const float*)d_in[8];
  const float* bu = (const float*)d_in[9];
  const float* Wd = (const float*)d_in[10];
  const float* bd = (const float*)d_in[11];
  const float* g1 = (const float*)d_in[12];
  const float* g2 = (const float*)d_in[13];

  char* p = (char*)d_ws;
  auto alloc = [&](size_t bytes) { char* r = p; p += (bytes + 255) & ~(size_t)255; return r; };
  u16*   BtQKV = (u16*)alloc((size_t)DQKV * 2048 * 2);
  u16*   WoT   = (u16*)alloc((size_t)2048 * 2048 * 2);
  u16*   WgT   = (u16*)alloc((size_t)8192 * 2048 * 2);
  u16*   WuT   = (u16*)alloc((size_t)8192 * 2048 * 2);
  u16*   WdT   = (u16*)alloc((size_t)2048 * 8192 * 2);
  u16*   xn    = (u16*)alloc((size_t)NROW * 2048 * 2);   // also hn
  u16*   QKV   = (u16*)alloc((size_t)NROW * DQKV * 2);
  u16*   Obuf  = (u16*)alloc((size_t)NROW * 2048 * 2);
  float* h     = (float*)alloc((size_t)NROW * 2048 * 4);
  u16*   gact  = (u16*)alloc((size_t)NROW * 8192 * 2);
  float* cosT  = (float*)alloc((size_t)S_LEN * 64 * 4);
  float* sinT  = (float*)alloc((size_t)S_LEN * 64 * 4);
  // Wd split-K temporaries ALIAS the front of the workspace: BtQKV(12.6M) +
  // WoT(8.4M) + WgT(33.6M) + part of WuT — all dead by the time the Wd GEMM
  // runs (transposes -> QKV -> attn -> Wo -> swiglu complete). 64 MB needed,
  // 88 MB available. Rewritten every call before being read -> replay-safe.
  float* wdt   = (float*)d_ws;

  dim3 tb(32, 8);
  transpose_f32_bf16<<<dim3(2048/32, 2048/32), tb, 0, stream>>>(Wq, BtQKV,                2048, 2048);
  transpose_f32_bf16<<<dim3( 512/32, 2048/32), tb, 0, stream>>>(Wk, BtQKV + 2048ull*2048, 2048,  512);
  transpose_f32_bf16<<<dim3( 512/32, 2048/32), tb, 0, stream>>>(Wv, BtQKV + 2560ull*2048, 2048,  512);
  transpose_f32_bf16<<<dim3(2048/32, 2048/32), tb, 0, stream>>>(Wo, WoT,                  2048, 2048);
  transpose_f32_bf16<<<dim3(8192/32, 2048/32), tb, 0, stream>>>(Wg, WgT,                  2048, 8192);
  transpose_f32_bf16<<<dim3(8192/32, 2048/32), tb, 0, stream>>>(Wu, WuT,                  2048, 8192);
  transpose_f32_bf16<<<dim3(2048/32, 8192/32), tb, 0, stream>>>(Wd, WdT,                  8192, 2048);

  rope_tables<<<(S_LEN * 64) / 256, 256, 0, stream>>>(cosT, sinT);

  rmsnorm_kernel<<<NROW, 256, 0, stream>>>(x, g1, xn);

  // QKV: M=4096, N=3072, K=2048
  gemmU<0><<<192, 512, 0, stream>>>(xn, BtQKV, nullptr, 2048, 2048, 3072,
                                    nullptr, nullptr, nullptr, QKV, nullptr);

  rope_apply<<<(NROW * 20 * 64) / 256, 256, 0, stream>>>(QKV, cosT, sinT);

  attn_kernel<<<512, 256, 0, stream>>>(QKV, Obuf);

  // Wo: M=4096, N=2048, K=2048, h = acc + x
  gemmU<1><<<128, 512, 0, stream>>>(Obuf, WoT, nullptr, 2048, 2048, 2048,
                                    nullptr, nullptr, x, nullptr, h);

  rmsnorm_kernel<<<NROW, 256, 0, stream>>>(h, g2, xn);

  // SwiGLU: M=4096, N=8192(g)+8192(u) combined per-128, K=2048
  gemmU<3><<<1024, 512, 0, stream>>>(xn, WgT, WuT, 2048, 2048, 8192,
                                     bg, bu, nullptr, gact, nullptr);

  // Wd: M=4096, N=2048, K=8192 split-K x2
  gemmU<2><<<256, 512, 0, stream>>>(gact, WdT, nullptr, 4096, 8192, 2048,
                                    nullptr, nullptr, nullptr, nullptr, wdt);

  combine_wd<<<2048, 256, 0, stream>>>(wdt, wdt + (size_t)NROW * 2048, h, bd,
                                       (float*)d_out);
}

// Round 9
// 812.307 us; speedup vs baseline: 1.0219x; 1.0219x over previous
//
#include <hip/hip_runtime.h>
#include <hip/hip_bf16.h>
#include <stdint.h>

#define S_LEN 2048
#define NROW  4096            // B*S
#define DQKV  3072            // 2048 Q + 512 K + 512 V

typedef unsigned short u16;
typedef __attribute__((ext_vector_type(8))) short bf16x8;
typedef __attribute__((ext_vector_type(4))) float f32x4;

__device__ __forceinline__ float bf2f(u16 v) {
  unsigned int u = ((unsigned int)v) << 16;
  return __builtin_bit_cast(float, u);
}
__device__ __forceinline__ u16 f2bf(float f) {
  unsigned int u = __builtin_bit_cast(unsigned int, f);
  u += 0x7FFFu + ((u >> 16) & 1u);
  return (u16)(u >> 16);
}
__device__ __forceinline__ void async16(const void* g, void* l) {
  __builtin_amdgcn_global_load_lds(
      (const __attribute__((address_space(1))) unsigned int*)(uintptr_t)g,
      (__attribute__((address_space(3))) unsigned int*)(uintptr_t)l, 16, 0, 0);
}
#define SB()   __builtin_amdgcn_sched_barrier(0)
#define WLG0   do { asm volatile("s_waitcnt lgkmcnt(0)" ::: "memory"); SB(); } while (0)
#define WLG8   do { asm volatile("s_waitcnt lgkmcnt(8)" ::: "memory"); } while (0)
#define WVM4   do { asm volatile("s_waitcnt vmcnt(4)" ::: "memory"); SB(); } while (0)
#define WVM0   do { asm volatile("s_waitcnt vmcnt(0)" ::: "memory"); SB(); } while (0)
#define BAR()  __builtin_amdgcn_s_barrier()

// ---------------- transpose f32 [R][C] -> bf16 [C][R] ----------------
__global__ __launch_bounds__(256) void transpose_f32_bf16(
    const float* __restrict__ in, u16* __restrict__ out, int R, int C) {
  __shared__ float t[32][33];
  const int bx = blockIdx.x * 32;
  const int by = blockIdx.y * 32;
  const int tx = threadIdx.x, ty = threadIdx.y;   // 32 x 8
#pragma unroll
  for (int i = 0; i < 32; i += 8)
    t[ty + i][tx] = in[(size_t)(by + ty + i) * C + bx + tx];
  __syncthreads();
#pragma unroll
  for (int i = 0; i < 32; i += 8)
    out[(size_t)(bx + ty + i) * R + by + tx] = f2bf(t[tx][ty + i]);
}

// ---------------- RoPE tables ----------------
__global__ __launch_bounds__(256) void rope_tables(float* __restrict__ cosT,
                                                   float* __restrict__ sinT) {
  int idx = blockIdx.x * 256 + threadIdx.x;   // 2048*64
  int i = idx & 63, s = idx >> 6;
  float inv = powf(10000.0f, -2.0f * (float)i / 128.0f);
  float ang = (float)s * inv;
  cosT[idx] = cosf(ang);
  sinT[idx] = sinf(ang);
}

// ---------------- RoPE in-place on QKV ----------------
__global__ __launch_bounds__(256) void rope_apply(u16* __restrict__ QKV,
                                                  const float* __restrict__ cosT,
                                                  const float* __restrict__ sinT) {
  int idx = blockIdx.x * 256 + threadIdx.x;        // NROW*20*64
  int i = idx & 63;
  int h20 = (idx >> 6) % 20;
  int row = idx / (64 * 20);
  int s = row & (S_LEN - 1);
  int col = (h20 < 16) ? (h20 * 128) : (2048 + (h20 - 16) * 128);
  size_t base = (size_t)row * DQKV + col;
  float v1 = bf2f(QKV[base + i]);
  float v2 = bf2f(QKV[base + 64 + i]);
  float c = cosT[s * 64 + i], sn = sinT[s * 64 + i];
  QKV[base + i]      = f2bf(v1 * c - v2 * sn);
  QKV[base + 64 + i] = f2bf(v1 * sn + v2 * c);
}

// ---------------- RMSNorm: f32 [rows][2048] -> bf16 ----------------
__global__ __launch_bounds__(256) void rmsnorm_kernel(const float* __restrict__ x,
                                                      const float* __restrict__ g,
                                                      u16* __restrict__ out) {
  const int row = blockIdx.x, tid = threadIdx.x;
  const float* xr = x + (size_t)row * 2048;
  float4 a = ((const float4*)xr)[tid * 2];
  float4 b = ((const float4*)xr)[tid * 2 + 1];
  float ss = a.x*a.x + a.y*a.y + a.z*a.z + a.w*a.w
           + b.x*b.x + b.y*b.y + b.z*b.z + b.w*b.w;
#pragma unroll
  for (int m = 1; m < 64; m <<= 1) ss += __shfl_xor(ss, m, 64);
  __shared__ float red[4];
  if ((tid & 63) == 0) red[tid >> 6] = ss;
  __syncthreads();
  float tot = red[0] + red[1] + red[2] + red[3];
  float rms = rsqrtf(tot * (1.0f / 2048.0f) + 1e-5f);
  const int c = tid * 8;
  float v[8] = {a.x,a.y,a.z,a.w,b.x,b.y,b.z,b.w};
  u16 o[8];
#pragma unroll
  for (int j = 0; j < 8; j++) o[j] = f2bf(v[j] * rms * g[c + j]);
  *(uint4*)(out + (size_t)row * 2048 + c) = *(uint4*)o;
}

// ================= uniform 256x256 GEMM, even-paced staging =================
// BM=BN=256, BK=64, 512 thr, 8 waves (2m x 4n), wave tile 128x64.
// Quadrants (m0n0)(m1n0)(m1n1)(m0n1); a0 CARRIED p0->p3 (no re-read; 24
// ds_read_b128/wave/K-tile). One half-tile staged per phase:
//   p0: Ah0(u+1)->other   p1: Bh1(u+1)->other
//   p2: Ah1(u+2)->cur (A dead after p1)   p3: Bh0(u+2)->cur (B dead after p2)
// One vmcnt(4) per tile at p3: certifies all of tile u+1 before its p0 reads,
// leaves tile u+2's two half-tiles in flight. Never drains to 0 in the loop.
// MODE 0: bf16 out. MODE 1: f32 out = acc + res. MODE 2: f32 out = acc
// (split-K, kslice = wg>>7). MODE 3: swiglu, B = g-panel || u-panel, LDS
// cross-wave epilogue writes silu(g+bg)*(u+bu).
template <int MODE>
__global__ __launch_bounds__(512, 2) void gemmU(
    const u16* __restrict__ A, const u16* __restrict__ Bt0, const u16* __restrict__ Bt1,
    int Klen, int Kstride, int Nout,
    const float* __restrict__ bias, const float* __restrict__ bias2,
    const float* __restrict__ res, u16* __restrict__ outb, float* __restrict__ outf) {
  __shared__ char ldsA[2 * 32768] __attribute__((aligned(16)));
  __shared__ char ldsB[2 * 32768] __attribute__((aligned(16)));
  const int t = threadIdx.x;
  const int nwg = gridDim.x;
  int wg = ((int)blockIdx.x & 7) * (nwg >> 3) + ((int)blockIdx.x >> 3);
  int kslice = 0;
  if (MODE == 2) { kslice = wg >> 7; wg &= 127; }
  const int m0 = (wg & 15) * 256;          // m-fast for XCD B-panel locality
  const int nIdx = wg >> 4;
  const int l = t & 63, w = t >> 6;
  const int wm = w >> 2, wn = w & 3;
  const int lr = l & 15, lg = l >> 4;

  const size_t Ks2 = (size_t)Kstride * 2;
  const int pr = t >> 3;                        // 0..63
  const int ckb = ((t & 7) ^ (pr & 7)) * 16;    // inverse-swizzled source chunk
  const int t16 = t * 16;
  const size_t koff = (size_t)kslice * 8192;    // bytes (4096 cols * 2B)
  const char* aSrc = (const char*)A + (size_t)(m0 + pr) * Ks2 + koff + ckb;
  const char* b0Src;
  const char* b1Src;
  if constexpr (MODE == 3) {
    b0Src = (const char*)Bt0 + (size_t)(nIdx * 128 + pr) * Ks2 + ckb;
    b1Src = (const char*)Bt1 + (size_t)(nIdx * 128 + pr) * Ks2 + ckb;
  } else {
    b0Src = (const char*)Bt0 + (size_t)(nIdx * 256 + pr) * Ks2 + koff + ckb;
    b1Src = b0Src + (size_t)128 * Ks2;
  }

  auto ST_A = [&](int h, int kt, int buf) {
    char* d = ldsA + buf * 32768 + h * 16384 + t16;
    const char* s = aSrc + (size_t)(h * 128) * Ks2 + (size_t)kt * 128;
    async16(s, d);
    async16(s + (size_t)64 * Ks2, d + 8192);
  };
  auto ST_B = [&](int h, int kt, int buf) {
    char* d = ldsB + buf * 32768 + h * 16384 + t16;
    const char* s = (h ? b1Src : b0Src) + (size_t)kt * 128;
    async16(s, d);
    async16(s + (size_t)64 * Ks2, d + 8192);
  };

  const int NT = Klen >> 6;
  // prologue mirrors steady-state issue order:
  //   [Ah1(0) Bh0(0)] (as p2/p3(u-2))  [Ah0(0) Bh1(0)] (as p0/p1(u-1))
  //   [Ah1(1) Bh0(1)] (as p2/p3(u-1))  then vmcnt(4) certifies tile 0.
  ST_A(1, 0, 0); ST_B(0, 0, 0); ST_A(0, 0, 0); ST_B(1, 0, 0);
  ST_A(1, 1, 1); ST_B(0, 1, 1);
  WVM4;
  BAR();

  const int key = lr & 7;
  const int c0 = (lg ^ key) * 16;
  const int c1 = ((4 + lg) ^ key) * 16;
  const int aBase = wm * 16384 + lr * 128;
  const int bBase = (wn >> 1) * 16384 + ((wn & 1) * 64 + lr) * 128;

  f32x4 acc[8][4] = {};

  for (int kt = 0; kt < NT; ++kt) {
    const int bufc = kt & 1, bufn = bufc ^ 1;
    const int t1 = (kt + 1 < NT) ? kt + 1 : 0;
    const int t2 = (kt + 2 < NT) ? kt + 2 : kt + 2 - NT;
    const char* sA = ldsA + bufc * 32768;
    const char* sB = ldsB + bufc * 32768;
    bf16x8 a0[4][2], a1[4][2], b0[2][2], b1[2][2];
    // ---- p0 (q m0n0): reads a0(8)+b0(4); stage Ah0(t+1)->other
#pragma unroll
    for (int m = 0; m < 4; m++) {
      a0[m][0] = *(const bf16x8*)(sA + aBase + m * 2048 + c0);
      a0[m][1] = *(const bf16x8*)(sA + aBase + m * 2048 + c1);
    }
#pragma unroll
    for (int n = 0; n < 2; n++) {
      b0[n][0] = *(const bf16x8*)(sB + bBase + n * 2048 + c0);
      b0[n][1] = *(const bf16x8*)(sB + bBase + n * 2048 + c1);
    }
    ST_A(0, t1, bufn);
    WLG8;
    SB(); BAR();
    WLG0;
    __builtin_amdgcn_s_setprio(1);
#pragma unroll
    for (int m = 0; m < 4; m++)
#pragma unroll
      for (int n = 0; n < 2; n++) {
        acc[m][n] = __builtin_amdgcn_mfma_f32_16x16x32_bf16(a0[m][0], b0[n][0], acc[m][n], 0, 0, 0);
        acc[m][n] = __builtin_amdgcn_mfma_f32_16x16x32_bf16(a0[m][1], b0[n][1], acc[m][n], 0, 0, 0);
      }
    __builtin_amdgcn_s_setprio(0);
    SB(); BAR();
    // ---- p1 (q m1n0): reads a1(8), carry b0; stage Bh1(t+1)->other
#pragma unroll
    for (int m = 0; m < 4; m++) {
      a1[m][0] = *(const bf16x8*)(sA + aBase + (4 + m) * 2048 + c0);
      a1[m][1] = *(const bf16x8*)(sA + aBase + (4 + m) * 2048 + c1);
    }
    ST_B(1, t1, bufn);
    SB(); BAR();
    WLG0;
    __builtin_amdgcn_s_setprio(1);
#pragma unroll
    for (int m = 0; m < 4; m++)
#pragma unroll
      for (int n = 0; n < 2; n++) {
        acc[4 + m][n] = __builtin_amdgcn_mfma_f32_16x16x32_bf16(a1[m][0], b0[n][0], acc[4 + m][n], 0, 0, 0);
        acc[4 + m][n] = __builtin_amdgcn_mfma_f32_16x16x32_bf16(a1[m][1], b0[n][1], acc[4 + m][n], 0, 0, 0);
      }
    __builtin_amdgcn_s_setprio(0);
    SB(); BAR();
    // ---- p2 (q m1n1): reads b1(4), carry a1; stage Ah1(t+2)->cur (A dead)
#pragma unroll
    for (int n = 0; n < 2; n++) {
      b1[n][0] = *(const bf16x8*)(sB + bBase + (2 + n) * 2048 + c0);
      b1[n][1] = *(const bf16x8*)(sB + bBase + (2 + n) * 2048 + c1);
    }
    ST_A(1, t2, bufc);
    SB(); BAR();
    WLG0;
    __builtin_amdgcn_s_setprio(1);
#pragma unroll
    for (int m = 0; m < 4; m++)
#pragma unroll
      for (int n = 0; n < 2; n++) {
        acc[4 + m][2 + n] = __builtin_amdgcn_mfma_f32_16x16x32_bf16(a1[m][0], b1[n][0], acc[4 + m][2 + n], 0, 0, 0);
        acc[4 + m][2 + n] = __builtin_amdgcn_mfma_f32_16x16x32_bf16(a1[m][1], b1[n][1], acc[4 + m][2 + n], 0, 0, 0);
      }
    __builtin_amdgcn_s_setprio(0);
    SB(); BAR();
    // ---- p3 (q m0n1): NO reads (a0, b1 carried); stage Bh0(t+2)->cur
    //      (B dead after p2); vmcnt(4) certifies ALL of tile t+1.
    ST_B(0, t2, bufc);
    WVM4;
    SB(); BAR();
    __builtin_amdgcn_s_setprio(1);
#pragma unroll
    for (int m = 0; m < 4; m++)
#pragma unroll
      for (int n = 0; n < 2; n++) {
        acc[m][2 + n] = __builtin_amdgcn_mfma_f32_16x16x32_bf16(a0[m][0], b1[n][0], acc[m][2 + n], 0, 0, 0);
        acc[m][2 + n] = __builtin_amdgcn_mfma_f32_16x16x32_bf16(a0[m][1], b1[n][1], acc[m][2 + n], 0, 0, 0);
      }
    __builtin_amdgcn_s_setprio(0);
    SB(); BAR();
  }

  WVM0;   // drain wrapped tail stages before epilogue / teardown

  if constexpr (MODE == 3) {
    BAR();
    auto epPtr = [&](int row, int cc8) -> u16* {
      char* base = (row < 128) ? ldsA : ldsB;
      int sc8 = cc8 ^ ((row ^ (row >> 3)) & 7);
      return (u16*)(base + (row & 127) * 512 + sc8 * 16);
    };
#pragma unroll
    for (int m = 0; m < 8; m++)
#pragma unroll
      for (int n = 0; n < 4; n++)
#pragma unroll
        for (int r = 0; r < 4; r++) {
          int row = wm * 128 + m * 16 + lg * 4 + r;
          int cc = wn * 64 + n * 16 + lr;
          epPtr(row, cc >> 3)[cc & 7] = f2bf(acc[m][n][r]);
        }
    BAR();
    const int cg = (t & 15) * 8;
    const int rb = (t >> 4) * 8;
    const int gcolb = nIdx * 128 + cg;
    float bgv[8], buv[8];
#pragma unroll
    for (int j = 0; j < 8; j++) { bgv[j] = bias[gcolb + j]; buv[j] = bias2[gcolb + j]; }
#pragma unroll
    for (int i = 0; i < 8; i++) {
      int row = rb + i;
      bf16x8 g8 = *(const bf16x8*)epPtr(row, cg >> 3);
      bf16x8 u8 = *(const bf16x8*)epPtr(row, (128 + cg) >> 3);
      u16 o[8];
#pragma unroll
      for (int j = 0; j < 8; j++) {
        float gv = bf2f((u16)g8[j]) + bgv[j];
        float uv = bf2f((u16)u8[j]) + buv[j];
        o[j] = f2bf(gv / (1.0f + __expf(-gv)) * uv);
      }
      *(uint4*)(outb + (size_t)(m0 + row) * Nout + gcolb) = *(uint4*)o;
    }
  } else {
    float* outfe = outf;
    if constexpr (MODE == 2) outfe = outf + (size_t)kslice * NROW * 2048;
    const int n0 = nIdx * 256;
#pragma unroll
    for (int m = 0; m < 8; m++) {
      const int row = m0 + wm * 128 + m * 16 + lg * 4;
#pragma unroll
      for (int n = 0; n < 4; n++) {
        const int col = n0 + wn * 64 + n * 16 + lr;
#pragma unroll
        for (int r = 0; r < 4; r++) {
          const size_t idx = (size_t)(row + r) * Nout + col;
          if (MODE == 0)      outb[idx] = f2bf(acc[m][n][r]);
          else if (MODE == 1) outfe[idx] = acc[m][n][r] + res[idx];
          else                outfe[idx] = acc[m][n][r];
        }
      }
    }
  }
}

// ---------------- Wd split-K combine: out = t0 + t1 + h + bd ----------------
__global__ __launch_bounds__(256) void combine_wd(
    const float* __restrict__ t0, const float* __restrict__ t1,
    const float* __restrict__ h, const float* __restrict__ bd,
    float* __restrict__ out) {
  const int stride = gridDim.x * 256;
  for (int i = blockIdx.x * 256 + threadIdx.x; i < NROW * 512; i += stride) {
    float4 a = ((const float4*)t0)[i];
    float4 b = ((const float4*)t1)[i];
    float4 c = ((const float4*)h)[i];
    float4 d = ((const float4*)bd)[i & 511];
    float4 o;
    o.x = a.x + b.x + c.x + d.x;
    o.y = a.y + b.y + c.y + d.y;
    o.z = a.z + b.z + c.z + d.z;
    o.w = a.w + b.w + c.w + d.w;
    ((float4*)out)[i] = o;
  }
}

// ---------------- Flash attention (causal, GQA kv = hq%4) ----------------
__global__ __launch_bounds__(256) void attn_kernel(const u16* __restrict__ QKV,
                                                   u16* __restrict__ O) {
  const int bid = blockIdx.x;
  const int half = bid >> 8, rr = bid & 255;
  const int bh = rr >> 3, tt = rr & 7;
  const int qtile = half ? (15 - tt) : tt;
  const int b = bh >> 4, hq = bh & 15, g = hq & 3;
  const int q0 = qtile * 128;
  const int tid = threadIdx.x, l = tid & 63, w = tid >> 6;
  const int lr = l & 15, lg = l >> 4;

  __shared__ u16 kT[64 * 128] __attribute__((aligned(16)));
  __shared__ u16 vT[128 * 64] __attribute__((aligned(16)));
  __shared__ u16 pT[4][32 * 72] __attribute__((aligned(16)));

  const float scale = 0.08838834764831845f;   // 1/sqrt(128)

  bf16x8 qF[2][4];
  const int qrow_base = b * S_LEN + q0 + w * 32;
#pragma unroll
  for (int mq = 0; mq < 2; mq++)
#pragma unroll
    for (int kk = 0; kk < 4; kk++)
      qF[mq][kk] = *(const bf16x8*)(QKV + (size_t)(qrow_base + mq * 16 + lr) * DQKV
                                    + hq * 128 + kk * 32 + lg * 8);

  f32x4 o_acc[2][8] = {};
  float m_run[2][4], l_run[2][4];
#pragma unroll
  for (int mq = 0; mq < 2; mq++)
#pragma unroll
    for (int r = 0; r < 4; r++) { m_run[mq][r] = -1e30f; l_run[mq][r] = 0.0f; }

  const int qmin_w = q0 + w * 32;
  const int nt = (q0 + 128) >> 6;

  for (int it = 0; it < nt; ++it) {
    const int t0 = it * 64;
    __syncthreads();
    {
      const int rbase = tid >> 3;
      const int c16 = (tid & 7) * 16;
#pragma unroll
      for (int pass = 0; pass < 2; ++pass) {
        const int r = rbase + pass * 32;
        const u16* src = QKV + (size_t)(b * S_LEN + t0 + r) * DQKV + 2048 + g * 128 + c16;
        const int rk = r & 7;
#pragma unroll
        for (int jj = 0; jj < 2; ++jj) {
          bf16x8 kv = *(const bf16x8*)(src + jj * 8);
          const int chunk = (c16 >> 3) + jj;
          *(bf16x8*)&kT[r * 128 + ((chunk ^ rk) << 3)] = kv;
        }
#pragma unroll
        for (int jj = 0; jj < 2; ++jj) {
          bf16x8 vv = *(const bf16x8*)(src + 512 + jj * 8);
#pragma unroll
          for (int j = 0; j < 8; ++j) {
            const int d = c16 + jj * 8 + j;
            const int keyv = (d ^ (d >> 4)) & 7;
            vT[d * 64 + (r & 7) + (((r >> 3) ^ keyv) << 3)] = (u16)vv[j];
          }
        }
      }
    }
    __syncthreads();

    if (t0 <= qmin_w + 31) {
      f32x4 sc[2][4] = {};
#pragma unroll
      for (int mt = 0; mt < 4; mt++) {
        const int tq = mt * 16 + lr;
        const int tk = tq & 7;
#pragma unroll
        for (int kk = 0; kk < 4; kk++) {
          bf16x8 kF = *(const bf16x8*)&kT[tq * 128 + (((kk * 4 + lg) ^ tk) << 3)];
          sc[0][mt] = __builtin_amdgcn_mfma_f32_16x16x32_bf16(qF[0][kk], kF, sc[0][mt], 0, 0, 0);
          sc[1][mt] = __builtin_amdgcn_mfma_f32_16x16x32_bf16(qF[1][kk], kF, sc[1][mt], 0, 0, 0);
        }
      }
      const bool needMask = (t0 + 63 > qmin_w);
#pragma unroll
      for (int mq = 0; mq < 2; mq++)
#pragma unroll
        for (int mt = 0; mt < 4; mt++)
#pragma unroll
          for (int r = 0; r < 4; r++) {
            float v = sc[mq][mt][r] * scale;
            if (needMask) {
              int qg = qmin_w + mq * 16 + lg * 4 + r;
              int tg = t0 + mt * 16 + lr;
              if (tg > qg) v = -1e30f;
            }
            sc[mq][mt][r] = v;
          }
#pragma unroll
      for (int mq = 0; mq < 2; mq++) {
        float al[4];
#pragma unroll
        for (int r = 0; r < 4; r++) {
          float tmax = fmaxf(fmaxf(sc[mq][0][r], sc[mq][1][r]),
                             fmaxf(sc[mq][2][r], sc[mq][3][r]));
#pragma unroll
          for (int m = 1; m < 16; m <<= 1) tmax = fmaxf(tmax, __shfl_xor(tmax, m, 64));
          float mn = fmaxf(m_run[mq][r], tmax);
          float a = __expf(m_run[mq][r] - mn);
          m_run[mq][r] = mn;
          float rs = 0.0f;
#pragma unroll
          for (int mt = 0; mt < 4; mt++) {
            float pv = __expf(sc[mq][mt][r] - mn);
            sc[mq][mt][r] = pv;
            rs += pv;
          }
#pragma unroll
          for (int m = 1; m < 16; m <<= 1) rs += __shfl_xor(rs, m, 64);
          l_run[mq][r] = l_run[mq][r] * a + rs;
          al[r] = a;
        }
#pragma unroll
        for (int n = 0; n < 8; n++)
#pragma unroll
          for (int r = 0; r < 4; r++) o_acc[mq][n][r] *= al[r];
#pragma unroll
        for (int mt = 0; mt < 4; mt++)
#pragma unroll
          for (int r = 0; r < 4; r++)
            pT[w][(mq * 16 + lg * 4 + r) * 72 + mt * 16 + lr] = f2bf(sc[mq][mt][r]);
      }
      bf16x8 pF[2][2];
#pragma unroll
      for (int mq = 0; mq < 2; mq++)
#pragma unroll
        for (int ktp = 0; ktp < 2; ktp++)
          pF[mq][ktp] = *(const bf16x8*)&pT[w][(mq * 16 + lr) * 72 + ktp * 32 + lg * 8];
#pragma unroll
      for (int ktp = 0; ktp < 2; ktp++)
#pragma unroll
        for (int n = 0; n < 8; n++) {
          const int d = n * 16 + lr;
          const int keyv = (d ^ (d >> 4)) & 7;
          bf16x8 vF = *(const bf16x8*)&vT[d * 64 + (((ktp * 4 + lg) ^ keyv) << 3)];
          o_acc[0][n] = __builtin_amdgcn_mfma_f32_16x16x32_bf16(pF[0][ktp], vF, o_acc[0][n], 0, 0, 0);
          o_acc[1][n] = __builtin_amdgcn_mfma_f32_16x16x32_bf16(pF[1][ktp], vF, o_acc[1][n], 0, 0, 0);
        }
    }
  }
#pragma unroll
  for (int mq = 0; mq < 2; mq++)
#pragma unroll
    for (int n = 0; n < 8; n++)
#pragma unroll
      for (int r = 0; r < 4; r++) {
        float v = o_acc[mq][n][r] / l_run[mq][r];
        int row = b * S_LEN + q0 + w * 32 + mq * 16 + lg * 4 + r;
        int col = hq * 128 + n * 16 + lr;
        O[(size_t)row * 2048 + col] = f2bf(v);
      }
}

// ---------------- launch ----------------
extern "C" void kernel_launch(void* const* d_in, const int* in_sizes, int n_in,
                              void* d_out, int out_size, void* d_ws, size_t ws_size,
                              hipStream_t stream) {
  const float* x  = (const float*)d_in[0];
  const float* Wq = (const float*)d_in[2];
  const float* Wk = (const float*)d_in[3];
  const float* Wv = (const float*)d_in[4];
  const float* Wo = (const float*)d_in[5];
  const float* Wg = (const float*)d_in[6];
  const float* bg = (const float*)d_in[7];
  const float* Wu = (const float*)d_in[8];
  const float* bu = (const float*)d_in[9];
  const float* Wd = (const float*)d_in[10];
  const float* bd = (const float*)d_in[11];
  const float* g1 = (const float*)d_in[12];
  const float* g2 = (const float*)d_in[13];

  char* p = (char*)d_ws;
  auto alloc = [&](size_t bytes) { char* r = p; p += (bytes + 255) & ~(size_t)255; return r; };
  u16*   BtQKV = (u16*)alloc((size_t)DQKV * 2048 * 2);
  u16*   WoT   = (u16*)alloc((size_t)2048 * 2048 * 2);
  u16*   WgT   = (u16*)alloc((size_t)8192 * 2048 * 2);
  u16*   WuT   = (u16*)alloc((size_t)8192 * 2048 * 2);
  u16*   WdT   = (u16*)alloc((size_t)2048 * 8192 * 2);
  u16*   xn    = (u16*)alloc((size_t)NROW * 2048 * 2);   // also hn
  u16*   QKV   = (u16*)alloc((size_t)NROW * DQKV * 2);
  u16*   Obuf  = (u16*)alloc((size_t)NROW * 2048 * 2);
  float* h     = (float*)alloc((size_t)NROW * 2048 * 4);
  u16*   gact  = (u16*)alloc((size_t)NROW * 8192 * 2);
  float* cosT  = (float*)alloc((size_t)S_LEN * 64 * 4);
  float* sinT  = (float*)alloc((size_t)S_LEN * 64 * 4);
  // Wd split-K temporaries ALIAS the front of the workspace (BtQKV..WuT, all
  // dead once swiglu has run). 64 MB needed, 88 MB available; fully rewritten
  // before read every call -> replay-safe.
  float* wdt   = (float*)d_ws;

  dim3 tb(32, 8);
  transpose_f32_bf16<<<dim3(2048/32, 2048/32), tb, 0, stream>>>(Wq, BtQKV,                2048, 2048);
  transpose_f32_bf16<<<dim3( 512/32, 2048/32), tb, 0, stream>>>(Wk, BtQKV + 2048ull*2048, 2048,  512);
  transpose_f32_bf16<<<dim3( 512/32, 2048/32), tb, 0, stream>>>(Wv, BtQKV + 2560ull*2048, 2048,  512);
  transpose_f32_bf16<<<dim3(2048/32, 2048/32), tb, 0, stream>>>(Wo, WoT,                  2048, 2048);
  transpose_f32_bf16<<<dim3(8192/32, 2048/32), tb, 0, stream>>>(Wg, WgT,                  2048, 8192);
  transpose_f32_bf16<<<dim3(8192/32, 2048/32), tb, 0, stream>>>(Wu, WuT,                  2048, 8192);
  transpose_f32_bf16<<<dim3(2048/32, 8192/32), tb, 0, stream>>>(Wd, WdT,                  8192, 2048);

  rope_tables<<<(S_LEN * 64) / 256, 256, 0, stream>>>(cosT, sinT);

  rmsnorm_kernel<<<NROW, 256, 0, stream>>>(x, g1, xn);

  // QKV: M=4096, N=3072, K=2048
  gemmU<0><<<192, 512, 0, stream>>>(xn, BtQKV, nullptr, 2048, 2048, 3072,
                                    nullptr, nullptr, nullptr, QKV, nullptr);

  rope_apply<<<(NROW * 20 * 64) / 256, 256, 0, stream>>>(QKV, cosT, sinT);

  attn_kernel<<<512, 256, 0, stream>>>(QKV, Obuf);

  // Wo: M=4096, N=2048, K=2048, h = acc + x
  gemmU<1><<<128, 512, 0, stream>>>(Obuf, WoT, nullptr, 2048, 2048, 2048,
                                    nullptr, nullptr, x, nullptr, h);

  rmsnorm_kernel<<<NROW, 256, 0, stream>>>(h, g2, xn);

  // SwiGLU: M=4096, N=8192(g)+8192(u) combined per-128, K=2048
  gemmU<3><<<1024, 512, 0, stream>>>(xn, WgT, WuT, 2048, 2048, 8192,
                                     bg, bu, nullptr, gact, nullptr);

  // Wd: M=4096, N=2048, K=8192 split-K x2
  gemmU<2><<<256, 512, 0, stream>>>(gact, WdT, nullptr, 4096, 8192, 2048,
                                    nullptr, nullptr, nullptr, nullptr, wdt);

  combine_wd<<<2048, 256, 0, stream>>>(wdt, wdt + (size_t)NROW * 2048, h, bd,
                                       (float*)d_out);
}

// Round 12
// 810.798 us; speedup vs baseline: 1.0238x; 1.0019x over previous
//
#include <hip/hip_runtime.h>
#include <hip/hip_bf16.h>
#include <stdint.h>

#define S_LEN 2048
#define NROW  4096            // B*S
#define DQKV  3072            // 2048 Q + 512 K + 512 V

typedef unsigned short u16;
typedef __attribute__((ext_vector_type(8))) short bf16x8;
typedef __attribute__((ext_vector_type(4))) float f32x4;

__device__ __forceinline__ float bf2f(u16 v) {
  unsigned int u = ((unsigned int)v) << 16;
  return __builtin_bit_cast(float, u);
}
__device__ __forceinline__ u16 f2bf(float f) {
  unsigned int u = __builtin_bit_cast(unsigned int, f);
  u += 0x7FFFu + ((u >> 16) & 1u);
  return (u16)(u >> 16);
}
__device__ __forceinline__ void async16(const void* g, void* l) {
  __builtin_amdgcn_global_load_lds(
      (const __attribute__((address_space(1))) unsigned int*)(uintptr_t)g,
      (__attribute__((address_space(3))) unsigned int*)(uintptr_t)l, 16, 0, 0);
}
#define SB()   __builtin_amdgcn_sched_barrier(0)
#define WLG0   do { asm volatile("s_waitcnt lgkmcnt(0)" ::: "memory"); SB(); } while (0)
#define WLG8   do { asm volatile("s_waitcnt lgkmcnt(8)" ::: "memory"); } while (0)
#define WVM4   do { asm volatile("s_waitcnt vmcnt(4)" ::: "memory"); SB(); } while (0)
#define WVM0   do { asm volatile("s_waitcnt vmcnt(0)" ::: "memory"); SB(); } while (0)
#define BAR()  __builtin_amdgcn_s_barrier()

// ---------------- transpose f32 [R][C] -> bf16 [C][R] ----------------
__global__ __launch_bounds__(256) void transpose_f32_bf16(
    const float* __restrict__ in, u16* __restrict__ out, int R, int C) {
  __shared__ float t[32][33];
  const int bx = blockIdx.x * 32;
  const int by = blockIdx.y * 32;
  const int tx = threadIdx.x, ty = threadIdx.y;   // 32 x 8
#pragma unroll
  for (int i = 0; i < 32; i += 8)
    t[ty + i][tx] = in[(size_t)(by + ty + i) * C + bx + tx];
  __syncthreads();
#pragma unroll
  for (int i = 0; i < 32; i += 8)
    out[(size_t)(bx + ty + i) * R + by + tx] = f2bf(t[tx][ty + i]);
}

// ---------------- RoPE tables ----------------
__global__ __launch_bounds__(256) void rope_tables(float* __restrict__ cosT,
                                                   float* __restrict__ sinT) {
  int idx = blockIdx.x * 256 + threadIdx.x;   // 2048*64
  int i = idx & 63, s = idx >> 6;
  float inv = powf(10000.0f, -2.0f * (float)i / 128.0f);
  float ang = (float)s * inv;
  cosT[idx] = cosf(ang);
  sinT[idx] = sinf(ang);
}

// ---------------- RoPE in-place on QKV ----------------
__global__ __launch_bounds__(256) void rope_apply(u16* __restrict__ QKV,
                                                  const float* __restrict__ cosT,
                                                  const float* __restrict__ sinT) {
  int idx = blockIdx.x * 256 + threadIdx.x;        // NROW*20*64
  int i = idx & 63;
  int h20 = (idx >> 6) % 20;
  int row = idx / (64 * 20);
  int s = row & (S_LEN - 1);
  int col = (h20 < 16) ? (h20 * 128) : (2048 + (h20 - 16) * 128);
  size_t base = (size_t)row * DQKV + col;
  float v1 = bf2f(QKV[base + i]);
  float v2 = bf2f(QKV[base + 64 + i]);
  float c = cosT[s * 64 + i], sn = sinT[s * 64 + i];
  QKV[base + i]      = f2bf(v1 * c - v2 * sn);
  QKV[base + 64 + i] = f2bf(v1 * sn + v2 * c);
}

// ---------------- RMSNorm: f32 [rows][2048] -> bf16 ----------------
__global__ __launch_bounds__(256) void rmsnorm_kernel(const float* __restrict__ x,
                                                      const float* __restrict__ g,
                                                      u16* __restrict__ out) {
  const int row = blockIdx.x, tid = threadIdx.x;
  const float* xr = x + (size_t)row * 2048;
  float4 a = ((const float4*)xr)[tid * 2];
  float4 b = ((const float4*)xr)[tid * 2 + 1];
  float ss = a.x*a.x + a.y*a.y + a.z*a.z + a.w*a.w
           + b.x*b.x + b.y*b.y + b.z*b.z + b.w*b.w;
#pragma unroll
  for (int m = 1; m < 64; m <<= 1) ss += __shfl_xor(ss, m, 64);
  __shared__ float red[4];
  if ((tid & 63) == 0) red[tid >> 6] = ss;
  __syncthreads();
  float tot = red[0] + red[1] + red[2] + red[3];
  float rms = rsqrtf(tot * (1.0f / 2048.0f) + 1e-5f);
  const int c = tid * 8;
  float v[8] = {a.x,a.y,a.z,a.w,b.x,b.y,b.z,b.w};
  u16 o[8];
#pragma unroll
  for (int j = 0; j < 8; j++) o[j] = f2bf(v[j] * rms * g[c + j]);
  *(uint4*)(out + (size_t)row * 2048 + c) = *(uint4*)o;
}

// ================= uniform 256x256 GEMM (r9 PROVEN schedule) =================
// BM=BN=256, BK=64, 512 thr, 8 waves (2m x 4n), wave tile 128x64.
// Quadrants (m0n0)(m1n0)(m1n1)(m0n1); a0/b0/a1/b1 carried (24 b128/wave/tile).
// Staging (replay-verified r9): p0: Ah0(t+1)->other, p1: Bh1(t+1)->other,
// p2: Ah1(t+2)->cur (A dead after p1), p3: Bh0(t+2)->cur (B dead after p2).
// One vmcnt(4) per tile at p3 certifies all of tile t+1. Never drains to 0.
// MODE 0: bf16 out. MODE 1: f32 out = acc + res. MODE 2: f32 out = acc
// (split-K x2: kslice = wg>>7, col window = kslice*Klen). MODE 3: swiglu,
// B = g-panel || u-panel, LDS cross-wave epilogue writes silu(g+bg)*(u+bu).
template <int MODE>
__global__ __launch_bounds__(512, 2) void gemmU(
    const u16* __restrict__ A, const u16* __restrict__ Bt0, const u16* __restrict__ Bt1,
    int Klen, int Kstride, int Nout,
    const float* __restrict__ bias, const float* __restrict__ bias2,
    const float* __restrict__ res, u16* __restrict__ outb, float* __restrict__ outf) {
  __shared__ char ldsA[2 * 32768] __attribute__((aligned(16)));
  __shared__ char ldsB[2 * 32768] __attribute__((aligned(16)));
  const int t = threadIdx.x;
  const int nwg = gridDim.x;
  int wg = ((int)blockIdx.x & 7) * (nwg >> 3) + ((int)blockIdx.x >> 3);
  int kslice = 0;
  if (MODE == 2) { kslice = wg >> 7; wg &= 127; }
  const int m0 = (wg & 15) * 256;          // m-fast for XCD B-panel locality
  const int nIdx = wg >> 4;
  const int l = t & 63, w = t >> 6;
  const int wm = w >> 2, wn = w & 3;
  const int lr = l & 15, lg = l >> 4;

  const size_t Ks2 = (size_t)Kstride * 2;
  const int pr = t >> 3;                        // 0..63
  const int ckb = ((t & 7) ^ (pr & 7)) * 16;    // inverse-swizzled source chunk
  const int t16 = t * 16;
  const size_t koff = (size_t)kslice * Klen * 2;   // byte offset of K window
  const char* aSrc = (const char*)A + (size_t)(m0 + pr) * Ks2 + koff + ckb;
  const char* b0Src;
  const char* b1Src;
  if constexpr (MODE == 3) {
    b0Src = (const char*)Bt0 + (size_t)(nIdx * 128 + pr) * Ks2 + ckb;
    b1Src = (const char*)Bt1 + (size_t)(nIdx * 128 + pr) * Ks2 + ckb;
  } else {
    b0Src = (const char*)Bt0 + (size_t)(nIdx * 256 + pr) * Ks2 + koff + ckb;
    b1Src = b0Src + (size_t)128 * Ks2;
  }

  auto ST_A = [&](int h, int kt, int buf) {
    char* d = ldsA + buf * 32768 + h * 16384 + t16;
    const char* s = aSrc + (size_t)(h * 128) * Ks2 + (size_t)kt * 128;
    async16(s, d);
    async16(s + (size_t)64 * Ks2, d + 8192);
  };
  auto ST_B = [&](int h, int kt, int buf) {
    char* d = ldsB + buf * 32768 + h * 16384 + t16;
    const char* s = (h ? b1Src : b0Src) + (size_t)kt * 128;
    async16(s, d);
    async16(s + (size_t)64 * Ks2, d + 8192);
  };

  const int NT = Klen >> 6;
  // r9 prologue (issue order mirrors steady state); WVM4 certifies tile 0.
  ST_A(1, 0, 0); ST_B(0, 0, 0); ST_A(0, 0, 0); ST_B(1, 0, 0);
  ST_A(1, 1, 1); ST_B(0, 1, 1);
  WVM4;
  BAR();

  const int key = lr & 7;
  const int c0 = (lg ^ key) * 16;
  const int c1 = ((4 + lg) ^ key) * 16;
  const int aBase = wm * 16384 + lr * 128;
  const int bBase = (wn >> 1) * 16384 + ((wn & 1) * 64 + lr) * 128;

  f32x4 acc[8][4] = {};

  for (int kt = 0; kt < NT; ++kt) {
    const int bufc = kt & 1, bufn = bufc ^ 1;
    const int t1 = (kt + 1 < NT) ? kt + 1 : 0;
    const int t2 = (kt + 2 < NT) ? kt + 2 : kt + 2 - NT;
    const char* sA = ldsA + bufc * 32768;
    const char* sB = ldsB + bufc * 32768;
    bf16x8 a0[4][2], a1[4][2], b0[2][2], b1[2][2];
    // ---- p0 (q m0n0): reads a0(8)+b0(4); stage Ah0(t+1)->other
#pragma unroll
    for (int m = 0; m < 4; m++) {
      a0[m][0] = *(const bf16x8*)(sA + aBase + m * 2048 + c0);
      a0[m][1] = *(const bf16x8*)(sA + aBase + m * 2048 + c1);
    }
#pragma unroll
    for (int n = 0; n < 2; n++) {
      b0[n][0] = *(const bf16x8*)(sB + bBase + n * 2048 + c0);
      b0[n][1] = *(const bf16x8*)(sB + bBase + n * 2048 + c1);
    }
    ST_A(0, t1, bufn);
    WLG8;
    SB(); BAR();
    WLG0;
    __builtin_amdgcn_s_setprio(1);
#pragma unroll
    for (int m = 0; m < 4; m++)
#pragma unroll
      for (int n = 0; n < 2; n++) {
        acc[m][n] = __builtin_amdgcn_mfma_f32_16x16x32_bf16(a0[m][0], b0[n][0], acc[m][n], 0, 0, 0);
        acc[m][n] = __builtin_amdgcn_mfma_f32_16x16x32_bf16(a0[m][1], b0[n][1], acc[m][n], 0, 0, 0);
      }
    __builtin_amdgcn_s_setprio(0);
    SB(); BAR();
    // ---- p1 (q m1n0): reads a1(8), carry b0; stage Bh1(t+1)->other
#pragma unroll
    for (int m = 0; m < 4; m++) {
      a1[m][0] = *(const bf16x8*)(sA + aBase + (4 + m) * 2048 + c0);
      a1[m][1] = *(const bf16x8*)(sA + aBase + (4 + m) * 2048 + c1);
    }
    ST_B(1, t1, bufn);
    SB(); BAR();
    WLG0;   // a1 retired -> A region death at p2 stage is safe
    __builtin_amdgcn_s_setprio(1);
#pragma unroll
    for (int m = 0; m < 4; m++)
#pragma unroll
      for (int n = 0; n < 2; n++) {
        acc[4 + m][n] = __builtin_amdgcn_mfma_f32_16x16x32_bf16(a1[m][0], b0[n][0], acc[4 + m][n], 0, 0, 0);
        acc[4 + m][n] = __builtin_amdgcn_mfma_f32_16x16x32_bf16(a1[m][1], b0[n][1], acc[4 + m][n], 0, 0, 0);
      }
    __builtin_amdgcn_s_setprio(0);
    SB(); BAR();
    // ---- p2 (q m1n1): reads b1(4), carry a1; stage Ah1(t+2)->cur (A dead)
#pragma unroll
    for (int n = 0; n < 2; n++) {
      b1[n][0] = *(const bf16x8*)(sB + bBase + (2 + n) * 2048 + c0);
      b1[n][1] = *(const bf16x8*)(sB + bBase + (2 + n) * 2048 + c1);
    }
    ST_A(1, t2, bufc);
    SB(); BAR();
    WLG0;   // b1 retired -> B region death at p3 stage is safe
    __builtin_amdgcn_s_setprio(1);
#pragma unroll
    for (int m = 0; m < 4; m++)
#pragma unroll
      for (int n = 0; n < 2; n++) {
        acc[4 + m][2 + n] = __builtin_amdgcn_mfma_f32_16x16x32_bf16(a1[m][0], b1[n][0], acc[4 + m][2 + n], 0, 0, 0);
        acc[4 + m][2 + n] = __builtin_amdgcn_mfma_f32_16x16x32_bf16(a1[m][1], b1[n][1], acc[4 + m][2 + n], 0, 0, 0);
      }
    __builtin_amdgcn_s_setprio(0);
    SB(); BAR();
    // ---- p3 (q m0n1): NO reads (a0, b1 carried); stage Bh0(t+2)->cur;
    //      vmcnt(4) certifies ALL of tile t+1 (oldest 8 of 12 outstanding).
    ST_B(0, t2, bufc);
    WVM4;
    SB(); BAR();
    __builtin_amdgcn_s_setprio(1);
#pragma unroll
    for (int m = 0; m < 4; m++)
#pragma unroll
      for (int n = 0; n < 2; n++) {
        acc[m][2 + n] = __builtin_amdgcn_mfma_f32_16x16x32_bf16(a0[m][0], b1[n][0], acc[m][2 + n], 0, 0, 0);
        acc[m][2 + n] = __builtin_amdgcn_mfma_f32_16x16x32_bf16(a0[m][1], b1[n][1], acc[m][2 + n], 0, 0, 0);
      }
    __builtin_amdgcn_s_setprio(0);
    SB(); BAR();
  }

  WVM0;   // drain wrapped tail stages before epilogue / teardown

  if constexpr (MODE == 3) {
    BAR();
    auto epPtr = [&](int row, int cc8) -> u16* {
      char* base = (row < 128) ? ldsA : ldsB;
      int sc8 = cc8 ^ ((row ^ (row >> 3)) & 7);
      return (u16*)(base + (row & 127) * 512 + sc8 * 16);
    };
#pragma unroll
    for (int m = 0; m < 8; m++)
#pragma unroll
      for (int n = 0; n < 4; n++)
#pragma unroll
        for (int r = 0; r < 4; r++) {
          int row = wm * 128 + m * 16 + lg * 4 + r;
          int cc = wn * 64 + n * 16 + lr;
          epPtr(row, cc >> 3)[cc & 7] = f2bf(acc[m][n][r]);
        }
    BAR();
    const int cg = (t & 15) * 8;
    const int rb = (t >> 4) * 8;
    const int gcolb = nIdx * 128 + cg;
    float bgv[8], buv[8];
#pragma unroll
    for (int j = 0; j < 8; j++) { bgv[j] = bias[gcolb + j]; buv[j] = bias2[gcolb + j]; }
#pragma unroll
    for (int i = 0; i < 8; i++) {
      int row = rb + i;
      bf16x8 g8 = *(const bf16x8*)epPtr(row, cg >> 3);
      bf16x8 u8 = *(const bf16x8*)epPtr(row, (128 + cg) >> 3);
      u16 o[8];
#pragma unroll
      for (int j = 0; j < 8; j++) {
        float gv = bf2f((u16)g8[j]) + bgv[j];
        float uv = bf2f((u16)u8[j]) + buv[j];
        o[j] = f2bf(gv / (1.0f + __expf(-gv)) * uv);
      }
      *(uint4*)(outb + (size_t)(m0 + row) * Nout + gcolb) = *(uint4*)o;
    }
  } else {
    float* outfe = outf;
    if constexpr (MODE == 2) outfe = outf + (size_t)kslice * NROW * 2048;
    const int n0 = nIdx * 256;
#pragma unroll
    for (int m = 0; m < 8; m++) {
      const int row = m0 + wm * 128 + m * 16 + lg * 4;
#pragma unroll
      for (int n = 0; n < 4; n++) {
        const int col = n0 + wn * 64 + n * 16 + lr;
#pragma unroll
        for (int r = 0; r < 4; r++) {
          const size_t idx = (size_t)(row + r) * Nout + col;
          if (MODE == 0)      outb[idx] = f2bf(acc[m][n][r]);
          else if (MODE == 1) outfe[idx] = acc[m][n][r] + res[idx];
          else                outfe[idx] = acc[m][n][r];
        }
      }
    }
  }
}

// -------- split-K combine: out = t0 + t1 + res + (bias ? bias[col] : 0) -----
__global__ __launch_bounds__(256) void combine2(
    const float* __restrict__ t0, const float* __restrict__ t1,
    const float* __restrict__ res, const float* __restrict__ bias,
    float* __restrict__ out) {
  const int stride = gridDim.x * 256;
  for (int i = blockIdx.x * 256 + threadIdx.x; i < NROW * 512; i += stride) {
    float4 a = ((const float4*)t0)[i];
    float4 b = ((const float4*)t1)[i];
    float4 c = ((const float4*)res)[i];
    float4 d;
    if (bias) d = ((const float4*)bias)[i & 511];
    else      d = make_float4(0.f, 0.f, 0.f, 0.f);
    float4 o;
    o.x = a.x + b.x + c.x + d.x;
    o.y = a.y + b.y + c.y + d.y;
    o.z = a.z + b.z + c.z + d.z;
    o.w = a.w + b.w + c.w + d.w;
    ((float4*)out)[i] = o;
  }
}

// ---------------- Flash attention (causal, GQA kv = hq%4) ----------------
__global__ __launch_bounds__(256) void attn_kernel(const u16* __restrict__ QKV,
                                                   u16* __restrict__ O) {
  const int bid = blockIdx.x;
  const int half = bid >> 8, rr = bid & 255;
  const int bh = rr >> 3, tt = rr & 7;
  const int qtile = half ? (15 - tt) : tt;
  const int b = bh >> 4, hq = bh & 15, g = hq & 3;
  const int q0 = qtile * 128;
  const int tid = threadIdx.x, l = tid & 63, w = tid >> 6;
  const int lr = l & 15, lg = l >> 4;

  __shared__ u16 kT[64 * 128] __attribute__((aligned(16)));
  __shared__ u16 vT[128 * 64] __attribute__((aligned(16)));
  __shared__ u16 pT[4][32 * 72] __attribute__((aligned(16)));

  const float scale = 0.08838834764831845f;   // 1/sqrt(128)

  bf16x8 qF[2][4];
  const int qrow_base = b * S_LEN + q0 + w * 32;
#pragma unroll
  for (int mq = 0; mq < 2; mq++)
#pragma unroll
    for (int kk = 0; kk < 4; kk++)
      qF[mq][kk] = *(const bf16x8*)(QKV + (size_t)(qrow_base + mq * 16 + lr) * DQKV
                                    + hq * 128 + kk * 32 + lg * 8);

  f32x4 o_acc[2][8] = {};
  float m_run[2][4], l_run[2][4];
#pragma unroll
  for (int mq = 0; mq < 2; mq++)
#pragma unroll
    for (int r = 0; r < 4; r++) { m_run[mq][r] = -1e30f; l_run[mq][r] = 0.0f; }

  const int qmin_w = q0 + w * 32;
  const int nt = (q0 + 128) >> 6;

  for (int it = 0; it < nt; ++it) {
    const int t0 = it * 64;
    __syncthreads();
    {
      const int rbase = tid >> 3;
      const int c16 = (tid & 7) * 16;
#pragma unroll
      for (int pass = 0; pass < 2; ++pass) {
        const int r = rbase + pass * 32;
        const u16* src = QKV + (size_t)(b * S_LEN + t0 + r) * DQKV + 2048 + g * 128 + c16;
        const int rk = r & 7;
#pragma unroll
        for (int jj = 0; jj < 2; ++jj) {
          bf16x8 kv = *(const bf16x8*)(src + jj * 8);
          const int chunk = (c16 >> 3) + jj;
          *(bf16x8*)&kT[r * 128 + ((chunk ^ rk) << 3)] = kv;
        }
#pragma unroll
        for (int jj = 0; jj < 2; ++jj) {
          bf16x8 vv = *(const bf16x8*)(src + 512 + jj * 8);
#pragma unroll
          for (int j = 0; j < 8; ++j) {
            const int d = c16 + jj * 8 + j;
            const int keyv = (d ^ (d >> 4)) & 7;
            vT[d * 64 + (r & 7) + (((r >> 3) ^ keyv) << 3)] = (u16)vv[j];
          }
        }
      }
    }
    __syncthreads();

    if (t0 <= qmin_w + 31) {
      f32x4 sc[2][4] = {};
#pragma unroll
      for (int mt = 0; mt < 4; mt++) {
        const int tq = mt * 16 + lr;
        const int tk = tq & 7;
#pragma unroll
        for (int kk = 0; kk < 4; kk++) {
          bf16x8 kF = *(const bf16x8*)&kT[tq * 128 + (((kk * 4 + lg) ^ tk) << 3)];
          sc[0][mt] = __builtin_amdgcn_mfma_f32_16x16x32_bf16(qF[0][kk], kF, sc[0][mt], 0, 0, 0);
          sc[1][mt] = __builtin_amdgcn_mfma_f32_16x16x32_bf16(qF[1][kk], kF, sc[1][mt], 0, 0, 0);
        }
      }
      const bool needMask = (t0 + 63 > qmin_w);
#pragma unroll
      for (int mq = 0; mq < 2; mq++)
#pragma unroll
        for (int mt = 0; mt < 4; mt++)
#pragma unroll
          for (int r = 0; r < 4; r++) {
            float v = sc[mq][mt][r] * scale;
            if (needMask) {
              int qg = qmin_w + mq * 16 + lg * 4 + r;
              int tg = t0 + mt * 16 + lr;
              if (tg > qg) v = -1e30f;
            }
            sc[mq][mt][r] = v;
          }
#pragma unroll
      for (int mq = 0; mq < 2; mq++) {
        float al[4];
#pragma unroll
        for (int r = 0; r < 4; r++) {
          float tmax = fmaxf(fmaxf(sc[mq][0][r], sc[mq][1][r]),
                             fmaxf(sc[mq][2][r], sc[mq][3][r]));
#pragma unroll
          for (int m = 1; m < 16; m <<= 1) tmax = fmaxf(tmax, __shfl_xor(tmax, m, 64));
          float mn = fmaxf(m_run[mq][r], tmax);
          float a = __expf(m_run[mq][r] - mn);
          m_run[mq][r] = mn;
          float rs = 0.0f;
#pragma unroll
          for (int mt = 0; mt < 4; mt++) {
            float pv = __expf(sc[mq][mt][r] - mn);
            sc[mq][mt][r] = pv;
            rs += pv;
          }
#pragma unroll
          for (int m = 1; m < 16; m <<= 1) rs += __shfl_xor(rs, m, 64);
          l_run[mq][r] = l_run[mq][r] * a + rs;
          al[r] = a;
        }
#pragma unroll
        for (int n = 0; n < 8; n++)
#pragma unroll
          for (int r = 0; r < 4; r++) o_acc[mq][n][r] *= al[r];
#pragma unroll
        for (int mt = 0; mt < 4; mt++)
#pragma unroll
          for (int r = 0; r < 4; r++)
            pT[w][(mq * 16 + lg * 4 + r) * 72 + mt * 16 + lr] = f2bf(sc[mq][mt][r]);
      }
      bf16x8 pF[2][2];
#pragma unroll
      for (int mq = 0; mq < 2; mq++)
#pragma unroll
        for (int ktp = 0; ktp < 2; ktp++)
          pF[mq][ktp] = *(const bf16x8*)&pT[w][(mq * 16 + lr) * 72 + ktp * 32 + lg * 8];
#pragma unroll
      for (int ktp = 0; ktp < 2; ktp++)
#pragma unroll
        for (int n = 0; n < 8; n++) {
          const int d = n * 16 + lr;
          const int keyv = (d ^ (d >> 4)) & 7;
          bf16x8 vF = *(const bf16x8*)&vT[d * 64 + (((ktp * 4 + lg) ^ keyv) << 3)];
          o_acc[0][n] = __builtin_amdgcn_mfma_f32_16x16x32_bf16(pF[0][ktp], vF, o_acc[0][n], 0, 0, 0);
          o_acc[1][n] = __builtin_amdgcn_mfma_f32_16x16x32_bf16(pF[1][ktp], vF, o_acc[1][n], 0, 0, 0);
        }
    }
  }
#pragma unroll
  for (int mq = 0; mq < 2; mq++)
#pragma unroll
    for (int n = 0; n < 8; n++)
#pragma unroll
      for (int r = 0; r < 4; r++) {
        float v = o_acc[mq][n][r] / l_run[mq][r];
        int row = b * S_LEN + q0 + w * 32 + mq * 16 + lg * 4 + r;
        int col = hq * 128 + n * 16 + lr;
        O[(size_t)row * 2048 + col] = f2bf(v);
      }
}

// ---------------- launch ----------------
extern "C" void kernel_launch(void* const* d_in, const int* in_sizes, int n_in,
                              void* d_out, int out_size, void* d_ws, size_t ws_size,
                              hipStream_t stream) {
  const float* x  = (const float*)d_in[0];
  const float* Wq = (const float*)d_in[2];
  const float* Wk = (const float*)d_in[3];
  const float* Wv = (const float*)d_in[4];
  const float* Wo = (const float*)d_in[5];
  const float* Wg = (const float*)d_in[6];
  const float* bg = (const float*)d_in[7];
  const float* Wu = (const float*)d_in[8];
  const float* bu = (const float*)d_in[9];
  const float* Wd = (const float*)d_in[10];
  const float* bd = (const float*)d_in[11];
  const float* g1 = (const float*)d_in[12];
  const float* g2 = (const float*)d_in[13];

  char* p = (char*)d_ws;
  auto alloc = [&](size_t bytes) { char* r = p; p += (bytes + 255) & ~(size_t)255; return r; };
  u16*   BtQKV = (u16*)alloc((size_t)DQKV * 2048 * 2);
  u16*   WoT   = (u16*)alloc((size_t)2048 * 2048 * 2);
  u16*   WgT   = (u16*)alloc((size_t)8192 * 2048 * 2);
  u16*   WuT   = (u16*)alloc((size_t)8192 * 2048 * 2);
  u16*   WdT   = (u16*)alloc((size_t)2048 * 8192 * 2);
  u16*   xn    = (u16*)alloc((size_t)NROW * 2048 * 2);   // also hn
  u16*   QKV   = (u16*)alloc((size_t)NROW * DQKV * 2);
  u16*   Obuf  = (u16*)alloc((size_t)NROW * 2048 * 2);
  float* h     = (float*)alloc((size_t)NROW * 2048 * 4);
  u16*   gact  = (u16*)alloc((size_t)NROW * 8192 * 2);
  float* cosT  = (float*)alloc((size_t)S_LEN * 64 * 4);
  float* sinT  = (float*)alloc((size_t)S_LEN * 64 * 4);
  // Wo split-K temporaries alias gact (64 MB, dead until swiglu rewrites it
  // after combine2 has consumed these). Wd split-K temporaries alias the
  // front of the workspace (BtQKV..WgT, dead once swiglu has run). Both are
  // fully rewritten before every read -> replay-safe.
  float* wot = (float*)gact;
  float* wdt = (float*)d_ws;

  dim3 tb(32, 8);
  transpose_f32_bf16<<<dim3(2048/32, 2048/32), tb, 0, stream>>>(Wq, BtQKV,                2048, 2048);
  transpose_f32_bf16<<<dim3( 512/32, 2048/32), tb, 0, stream>>>(Wk, BtQKV + 2048ull*2048, 2048,  512);
  transpose_f32_bf16<<<dim3( 512/32, 2048/32), tb, 0, stream>>>(Wv, BtQKV + 2560ull*2048, 2048,  512);
  transpose_f32_bf16<<<dim3(2048/32, 2048/32), tb, 0, stream>>>(Wo, WoT,                  2048, 2048);
  transpose_f32_bf16<<<dim3(8192/32, 2048/32), tb, 0, stream>>>(Wg, WgT,                  2048, 8192);
  transpose_f32_bf16<<<dim3(8192/32, 2048/32), tb, 0, stream>>>(Wu, WuT,                  2048, 8192);
  transpose_f32_bf16<<<dim3(2048/32, 8192/32), tb, 0, stream>>>(Wd, WdT,                  8192, 2048);

  rope_tables<<<(S_LEN * 64) / 256, 256, 0, stream>>>(cosT, sinT);

  rmsnorm_kernel<<<NROW, 256, 0, stream>>>(x, g1, xn);

  // QKV: M=4096, N=3072, K=2048
  gemmU<0><<<192, 512, 0, stream>>>(xn, BtQKV, nullptr, 2048, 2048, 3072,
                                    nullptr, nullptr, nullptr, QKV, nullptr);

  rope_apply<<<(NROW * 20 * 64) / 256, 256, 0, stream>>>(QKV, cosT, sinT);

  attn_kernel<<<512, 256, 0, stream>>>(QKV, Obuf);

  // Wo: M=4096, N=2048, K=2048 split-K x2 (256 blocks -> full CU occupancy)
  gemmU<2><<<256, 512, 0, stream>>>(Obuf, WoT, nullptr, 1024, 2048, 2048,
                                    nullptr, nullptr, nullptr, nullptr, wot);
  combine2<<<2048, 256, 0, stream>>>(wot, wot + (size_t)NROW * 2048, x, nullptr, h);

  rmsnorm_kernel<<<NROW, 256, 0, stream>>>(h, g2, xn);

  // SwiGLU: M=4096, N=8192(g)+8192(u) combined per-128, K=2048
  gemmU<3><<<1024, 512, 0, stream>>>(xn, WgT, WuT, 2048, 2048, 8192,
                                     bg, bu, nullptr, gact, nullptr);

  // Wd: M=4096, N=2048, K=8192 split-K x2
  gemmU<2><<<256, 512, 0, stream>>>(gact, WdT, nullptr, 4096, 8192, 2048,
                                    nullptr, nullptr, nullptr, nullptr, wdt);

  combine2<<<2048, 256, 0, stream>>>(wdt, wdt + (size_t)NROW * 2048, h, bd,
                                     (float*)d_out);
}